// Round 15
// baseline (884.427 us; speedup 1.0000x reference)
//
#include <hip/hip_runtime.h>

// NetG: seq2seq GRU (enc GRU -> +noise -> dec GRU -> FC head)
// B=512, T=256, H=256, D=3.
//
// R25 = R24 (fused enc+dec, 729us kernel / 813 total) + phase-3 FUSED
//   projection.
//   R24 post-mortem: recurrence loop confirmed at its measured optimum
//   (~3420 cyc/step, jointly bound LDS~70%/VALU~59%/MFMA~50% of active
//   CU; 9 structural variants all regress). Remaining addressable time:
//   ~80us of proj_kernel + launch gaps. Block g owns ALL of Y[g] (2MB,
//   L3-resident after the nontemporal stream) -> project it in-kernel:
//   1024 thr x 4 rows x (32 b128 loads + 768 scalar-W_fc MACs) ~ 5us
//   compute/block, reads L3-warm. Same read pattern + math order as the
//   old proj_kernel (absmax identical). Own-block R-after-W through the
//   same CU's write-through L1/L2 after __syncthreads - no fence needed.
// Frozen (R17/R24): 32 blocks x 1024 thr (16 waves, 1 tile/wave,
// 4/SIMD), NBATCH=16; gate-r k=0..3 LDS frags + k=4..7 global prefetch
// (prep_wr); z,n A-frags resident (64 AGPR); full-width h fragment
// layout, one barrier/step; bias-column x MFMA (q==0 lanes); native
// v_exp gates; interleaved epilogue -> x-step MFMA re-init; incremental
// Y pointers; fp32 register h carry; enc->dec handoff in registers;
// X_f in a 2nd LDS buffer (147.7KB); nontemporal Y stores.

#define B_TOT 512
#define T_LEN 256
#define HID 256
#define NBATCH 16
#define NTHREADS 1024
#define NBLK 32

#define XT 64
#define XSLOTS (T_LEN + 1)
#define HBUF (NBATCH * HID)

// LDS partition (units: shorts)
#define WR_OFF 0               // gate-r k=0..3 frags: 16*4*64*8 = 32768
#define H_OFF  32768           // 2 x 4096
#define X1_OFF 40960           // enc x: 257 x 64 = 16448
#define X2_OFF 57408           // dec x: 257 x 64 = 16448
#define SMEM_SHORTS (X2_OFF + XSLOTS * XT)   // 73856
#define SMEM_BYTES  (SMEM_SHORTS * 2)        // 147712 B <= 160 KiB

typedef __attribute__((ext_vector_type(4))) float f32x4;
typedef __attribute__((ext_vector_type(8))) short shortx8;
typedef __attribute__((ext_vector_type(4))) short i16x4;
typedef __attribute__((ext_vector_type(4))) unsigned short ushortx4;
typedef __attribute__((ext_vector_type(8))) unsigned short ushortx8;

#if __has_builtin(__builtin_amdgcn_mfma_f32_16x16x16_bf16)
#define HAVE_K16 1
#define MFMA_X(A, B, C) __builtin_amdgcn_mfma_f32_16x16x16_bf16((A), (B), (C), 0, 0, 0)
#elif __has_builtin(__builtin_amdgcn_mfma_f32_16x16x16bf16_1k)
#define HAVE_K16 1
#define MFMA_X(A, B, C) __builtin_amdgcn_mfma_f32_16x16x16bf16_1k((A), (B), (C), 0, 0, 0)
#else
#define HAVE_K16 0
#endif

__device__ __forceinline__ unsigned short f2bf(float x) {
    unsigned u = __float_as_uint(x);
    u += 0x7FFF + ((u >> 16) & 1);   // RNE
    return (unsigned short)(u >> 16);
}
__device__ __forceinline__ float bf2f(unsigned short s) {
    return __uint_as_float(((unsigned)s) << 16);
}
__device__ __forceinline__ float fastrcp(float x) {
#if __has_builtin(__builtin_amdgcn_rcpf)
    return __builtin_amdgcn_rcpf(x);
#else
    return 1.0f / x;
#endif
}
__device__ __forceinline__ float exp2raw(float y) {
#if __has_builtin(__builtin_amdgcn_exp2f)
    return __builtin_amdgcn_exp2f(y);
#else
    return __expf(y * 0.69314718056f);
#endif
}
__device__ __forceinline__ float sigmoid_(float x) {
    return fastrcp(1.0f + exp2raw(x * -1.44269504f));
}
__device__ __forceinline__ float tanh_(float x) {
    return 2.0f * fastrcp(1.0f + exp2raw(x * -2.88539008f)) - 1.0f;
}

// Pack gate-r (rows 0..255 of W_hh), K-half k=4..7, into per-lane fragment
// layout: dst[((ht*4+kk)*64+lane)*8+j] = bf16(W[ht*16+(lane&15)][(kk+4)*32+(lane>>4)*8+j])
__global__ __launch_bounds__(256) void prep_wr(
    const float* __restrict__ Whh_enc, const float* __restrict__ Whh_dec,
    unsigned short* __restrict__ wr_enc, unsigned short* __restrict__ wr_dec)
{
    int idx = blockIdx.x * 256 + threadIdx.x;    // 0..8191
    int gru = idx >> 12;
    int rem = idx & 4095;                        // (ht*4+kk)*64 + lane
    int lane = rem & 63;
    int kk = (rem >> 6) & 3;
    int ht = rem >> 8;
    const float* W = gru ? Whh_dec : Whh_enc;
    unsigned short* dst = gru ? wr_dec : wr_enc;
    int row = ht * 16 + (lane & 15);
    int col = (kk + 4) * 32 + (lane >> 4) * 8;
    const float* src = W + (size_t)row * 256 + col;
    ushortx8 v;
    #pragma unroll
    for (int j = 0; j < 8; ++j) v[j] = f2bf(src[j]);
    *(ushortx8*)(dst + (size_t)rem * 8) = v;
}

__global__ __launch_bounds__(NTHREADS, 1) void gru_fused(
    const float* __restrict__ X_p,     // [512][256][3]
    const float* __restrict__ X_f,     // [512][256][3]
    const float* __restrict__ Whh_e,   // [768][256] gates r,z,n
    const float* __restrict__ Whh_d,
    const float* __restrict__ Wih_e,   // [768][3]
    const float* __restrict__ Wih_d,
    const float* __restrict__ bih_e,   // [768]
    const float* __restrict__ bih_d,
    const float* __restrict__ bhh_e,   // [768]
    const float* __restrict__ bhh_d,
    const unsigned short* __restrict__ wr_e, // gate-r k=4..7 frags
    const unsigned short* __restrict__ wr_d,
    const float* __restrict__ noise,   // [512][256]
    unsigned short* __restrict__ Yout, // [32][256][16][256] bf16 (ws)
    const float* __restrict__ W_fc,    // [3][256]
    const float* __restrict__ b_fc,    // [3]
    float* __restrict__ out)           // [512][256][3]
{
    extern __shared__ unsigned short smem[];
    unsigned short* shWr = smem + WR_OFF;
    unsigned short* shH  = smem + H_OFF;

    const int tid  = threadIdx.x;
    const int g    = blockIdx.x;
    const int w    = tid >> 6;        // wave 0..15; owns hidden tile ht = w
    const int lane = tid & 63;
    const int c    = lane & 15;
    const int q    = lane >> 4;
    const int ht   = w;

    // ---- stage BOTH x sequences into LDS (dec shift baked into X2) ----
    for (int idx = tid; idx < NBATCH * XSLOTS * 2; idx += NTHREADS) {
        int half = idx >= NBATCH * XSLOTS;
        int rem = half ? idx - NBATCH * XSLOTS : idx;
        int t = rem >> 4, cc = rem & 15;
        int ts = half ? (t - 1) : t;
        const float* Xsrc = half ? X_f : X_p;
        float x0 = 0.0f, x1 = 0.0f, x2 = 0.0f;
        if (ts >= 0 && ts < T_LEN) {
            const float* xp = Xsrc + ((size_t)(g * NBATCH + cc) * T_LEN + ts) * 3;
            x0 = xp[0]; x1 = xp[1]; x2 = xp[2];
        }
        ushortx4 v = {f2bf(x0), f2bf(x1), f2bf(x2), (unsigned short)0x3F80};
        *(ushortx4*)&smem[(half ? X2_OFF : X1_OFF) + t * XT + cc * 4] = v;
    }

    // ---- loop-invariant lane constants ----
    int woff;
    {
        int kk = ht >> 1;
        int qq = ((ht & 1) << 1) | (q >> 1);
        woff = ((kk * 4 + qq) * 16 + c) * 8 + (q & 1) * 4;
    }
    const int bbase = q * 128 + c * 8;
    const unsigned short* ab = shWr + ((size_t)(ht * 4) * 64 + lane) * 8;
    const f32x4 zc = {0.0f, 0.0f, 0.0f, 0.0f};

    float hold0 = 0.0f, hold1 = 0.0f, hold2 = 0.0f, hold3 = 0.0f;

    for (int phase = 0; phase < 2; ++phase) {
        const float* W_hh = phase ? Whh_d : Whh_e;
        const float* W_ih = phase ? Wih_d : Wih_e;
        const float* b_ih = phase ? bih_d : bih_e;
        const float* b_hh = phase ? bhh_d : bhh_e;
        const unsigned short* Wr4 = phase ? wr_d : wr_e;
        const unsigned short* shX = smem + (phase ? X2_OFF : X1_OFF);

        __syncthreads();   // phase 1: prior-phase reads done before restage

        // ---- gate-r k=0..3 frags -> LDS (each wave stages its tile) ----
        {
            int row = ht * 16 + c;                      // gate r
            const float* wp = W_hh + (size_t)row * 256 + q * 8;
            #pragma unroll
            for (int k = 0; k < 4; ++k) {
                const f32x4* p = (const f32x4*)(wp + k * 32);
                f32x4 f0 = p[0];
                f32x4 f1 = p[1];
                shortx8 a;
                a[0] = (short)f2bf(f0[0]); a[1] = (short)f2bf(f0[1]);
                a[2] = (short)f2bf(f0[2]); a[3] = (short)f2bf(f0[3]);
                a[4] = (short)f2bf(f1[0]); a[5] = (short)f2bf(f1[1]);
                a[6] = (short)f2bf(f1[2]); a[7] = (short)f2bf(f1[3]);
                *(shortx8*)&shWr[((ht * 4 + k) * 64 + lane) * 8] = a;
            }
        }

        // ---- gates z,n A-frags resident (64 regs) ----
        shortx8 Wf[2][8];   // [z|n][k]
        #pragma unroll
        for (int gg = 0; gg < 2; ++gg) {
            int row = (gg + 1) * 256 + ht * 16 + c;
            const float* wp = W_hh + (size_t)row * 256 + q * 8;
            #pragma unroll
            for (int k = 0; k < 8; ++k) {
                const f32x4* p = (const f32x4*)(wp + k * 32);
                f32x4 f0 = p[0];
                f32x4 f1 = p[1];
                shortx8 a;
                a[0] = (short)f2bf(f0[0]); a[1] = (short)f2bf(f0[1]);
                a[2] = (short)f2bf(f0[2]); a[3] = (short)f2bf(f0[3]);
                a[4] = (short)f2bf(f1[0]); a[5] = (short)f2bf(f1[1]);
                a[6] = (short)f2bf(f1[2]); a[7] = (short)f2bf(f1[3]);
                Wf[gg][k] = a;
            }
        }

        // ---- x/bias A-frags (q==0 lanes carry data; others zero) ----
#if HAVE_K16
        i16x4 ax[3];
#else
        shortx8 ax[3];
#endif
        {
            int rr_ = ht * 16 + c;
            int rowr = rr_, rowz = 256 + rr_, rown = 512 + rr_;
            short r0 = 0, r1 = 0, r2 = 0, r3 = 0, z0 = 0, z1 = 0, z2 = 0, z3 = 0;
            short n0 = 0, n1 = 0, n2 = 0, n3 = 0;
            if (q == 0) {
                r0 = (short)f2bf(W_ih[rowr * 3 + 0]);
                r1 = (short)f2bf(W_ih[rowr * 3 + 1]);
                r2 = (short)f2bf(W_ih[rowr * 3 + 2]);
                r3 = (short)f2bf(b_ih[rowr] + b_hh[rowr]);
                z0 = (short)f2bf(W_ih[rowz * 3 + 0]);
                z1 = (short)f2bf(W_ih[rowz * 3 + 1]);
                z2 = (short)f2bf(W_ih[rowz * 3 + 2]);
                z3 = (short)f2bf(b_ih[rowz] + b_hh[rowz]);
                n0 = (short)f2bf(W_ih[rown * 3 + 0]);
                n1 = (short)f2bf(W_ih[rown * 3 + 1]);
                n2 = (short)f2bf(W_ih[rown * 3 + 2]);
                n3 = (short)f2bf(b_ih[rown]);
            }
#if HAVE_K16
            ax[0] = i16x4{r0, r1, r2, r3};
            ax[1] = i16x4{z0, z1, z2, z3};
            ax[2] = i16x4{n0, n1, n2, n3};
#else
            ax[0] = shortx8{r0, r1, r2, r3, 0, 0, 0, 0};
            ax[1] = shortx8{z0, z1, z2, z3, 0, 0, 0, 0};
            ax[2] = shortx8{n0, n1, n2, n3, 0, 0, 0, 0};
#endif
        }

        // ---- nh-bias register constants ----
        f32x4 nhb = *(const f32x4*)(b_hh + 512 + ht * 16 + q * 4);

        // ---- phase h0: enc = 0; dec = enc-final (regs, exact) + noise ----
        if (phase == 0) {
            hold0 = hold1 = hold2 = hold3 = 0.0f;
        } else {
            int b = g * NBATCH + c;
            int dim0 = ht * 16 + q * 4;
            f32x4 nz = *(const f32x4*)(noise + (size_t)b * HID + dim0);
            hold0 += nz[0]; hold1 += nz[1]; hold2 += nz[2]; hold3 += nz[3];
        }
        {
            ushortx4 hb16 = {f2bf(hold0), f2bf(hold1), f2bf(hold2), f2bf(hold3)};
            *(ushortx4*)&shH[woff] = hb16;   // parity buffer 0
        }

        // ---- incremental decoder Y pointer (phase 1 only) ----
        unsigned short* yp = Yout + ((size_t)g * T_LEN * NBATCH + c) * HID
                           + ht * 16 + q * 4;

        const unsigned short* gb = Wr4 + ((size_t)(ht * 4) * 64 + lane) * 8;

        __syncthreads();

        // ---- x-step for t=0 ----
        f32x4 acc0, acc1, acc2, acc3;   // r, z, nh, nx
        {
#if HAVE_K16
            i16x4 bx = *(const i16x4*)&shX[c * 4];
            acc0 = MFMA_X(ax[0], bx, zc);
            acc1 = MFMA_X(ax[1], bx, zc);
            acc3 = MFMA_X(ax[2], bx, zc);
#else
            ushortx4 xv = *(const ushortx4*)&shX[c * 4];
            shortx8 bx = (q == 0)
                ? shortx8{(short)xv[0], (short)xv[1], (short)xv[2], (short)xv[3], 0, 0, 0, 0}
                : shortx8{0, 0, 0, 0, 0, 0, 0, 0};
            acc0 = __builtin_amdgcn_mfma_f32_16x16x32_bf16(ax[0], bx, zc, 0, 0, 0);
            acc1 = __builtin_amdgcn_mfma_f32_16x16x32_bf16(ax[1], bx, zc, 0, 0, 0);
            acc3 = __builtin_amdgcn_mfma_f32_16x16x32_bf16(ax[2], bx, zc, 0, 0, 0);
#endif
        }

        int xidx = XT + c * 4;   // x slot for step t+1 (incremental)

        // ---- recurrence (R17 body, verbatim) ----
        for (int t = 0; t < T_LEN; ++t) {
            const unsigned short* brow = shH + (t & 1) * HBUF + bbase;
            unsigned short* hn = shH + ((t + 1) & 1) * HBUF;

            // gate-r k=4..7 from global: issued at step start, consumed
            // after the LDS half (proven prefetch timing)
            shortx8 gr[4];
            #pragma unroll
            for (int kk = 0; kk < 4; ++kk)
                gr[kk] = *(const shortx8*)(gb + kk * 512);

            acc2 = nhb;

            // k=0..3: gate-r from LDS
            #pragma unroll
            for (int k = 0; k < 4; ++k) {
                shortx8 bf = *(const shortx8*)(brow + k * 512);
                shortx8 ar = *(const shortx8*)(ab + k * 512);
                acc0 = __builtin_amdgcn_mfma_f32_16x16x32_bf16(ar,       bf, acc0, 0, 0, 0);
                acc1 = __builtin_amdgcn_mfma_f32_16x16x32_bf16(Wf[0][k], bf, acc1, 0, 0, 0);
                acc2 = __builtin_amdgcn_mfma_f32_16x16x32_bf16(Wf[1][k], bf, acc2, 0, 0, 0);
            }
            // k=4..7: gate-r from the global prefetch
            #pragma unroll
            for (int k = 4; k < 8; ++k) {
                shortx8 bf = *(const shortx8*)(brow + k * 512);
                acc0 = __builtin_amdgcn_mfma_f32_16x16x32_bf16(gr[k - 4], bf, acc0, 0, 0, 0);
                acc1 = __builtin_amdgcn_mfma_f32_16x16x32_bf16(Wf[0][k],  bf, acc1, 0, 0, 0);
                acc2 = __builtin_amdgcn_mfma_f32_16x16x32_bf16(Wf[1][k],  bf, acc2, 0, 0, 0);
            }

            // bx for step t+1
#if HAVE_K16
            i16x4 bxn = *(const i16x4*)&shX[xidx];
#else
            ushortx4 xvn = *(const ushortx4*)&shX[xidx];
            shortx8 bxn = (q == 0)
                ? shortx8{(short)xvn[0], (short)xvn[1], (short)xvn[2], (short)xvn[3], 0, 0, 0, 0}
                : shortx8{0, 0, 0, 0, 0, 0, 0, 0};
#endif
            xidx += XT;

            // ---- epilogue (4 values) ----
            {
                float rr, zz, nn;
                rr = sigmoid_(acc0[0]); zz = sigmoid_(acc1[0]);
                nn = tanh_(acc3[0] + rr * acc2[0]);
                hold0 = nn + zz * (hold0 - nn);
                rr = sigmoid_(acc0[1]); zz = sigmoid_(acc1[1]);
                nn = tanh_(acc3[1] + rr * acc2[1]);
                hold1 = nn + zz * (hold1 - nn);
                rr = sigmoid_(acc0[2]); zz = sigmoid_(acc1[2]);
                nn = tanh_(acc3[2] + rr * acc2[2]);
                hold2 = nn + zz * (hold2 - nn);
                rr = sigmoid_(acc0[3]); zz = sigmoid_(acc1[3]);
                nn = tanh_(acc3[3] + rr * acc2[3]);
                hold3 = nn + zz * (hold3 - nn);
                ushortx4 hb16 = {f2bf(hold0), f2bf(hold1), f2bf(hold2), f2bf(hold3)};
                *(ushortx4*)(hn + woff) = hb16;
                if (phase) {
                    __builtin_nontemporal_store(hb16, (ushortx4*)yp);
                    yp += NBATCH * HID;   // stride 4096 shorts per step
                }
            }

            // x-step re-init for t+1 (independent MFMAs under trans tail)
#if HAVE_K16
            acc0 = MFMA_X(ax[0], bxn, zc);
            acc1 = MFMA_X(ax[1], bxn, zc);
            acc3 = MFMA_X(ax[2], bxn, zc);
#else
            acc0 = __builtin_amdgcn_mfma_f32_16x16x32_bf16(ax[0], bxn, zc, 0, 0, 0);
            acc1 = __builtin_amdgcn_mfma_f32_16x16x32_bf16(ax[1], bxn, zc, 0, 0, 0);
            acc3 = __builtin_amdgcn_mfma_f32_16x16x32_bf16(ax[2], bxn, zc, 0, 0, 0);
#endif
            __syncthreads();
        }
    }

    // ---- phase 3: project this block's own Y (L2/L3-warm) ----
    // Y row r (= t*16+b16, 0..4095) of group g; same math order as the
    // old proj_kernel -> identical numerics. Own-block R-after-W: stores
    // are vmcnt-drained at the last __syncthreads; same-CU L1 is
    // write-through -> coherent with own stores.
    __syncthreads();
    #pragma unroll
    for (int i = 0; i < 4; ++i) {
        int rloc = i * NTHREADS + tid;           // 0..4095
        int b16 = rloc & 15;
        int t = rloc >> 4;
        const unsigned short* y = Yout + ((size_t)g * T_LEN * NBATCH + rloc) * HID;
        float a0 = b_fc[0], a1 = b_fc[1], a2 = b_fc[2];
        #pragma unroll 4
        for (int k8 = 0; k8 < 32; ++k8) {
            ushortx8 v = *(const ushortx8*)(y + k8 * 8);
            #pragma unroll
            for (int j = 0; j < 8; ++j) {
                float f = bf2f(v[j]);
                int k = k8 * 8 + j;
                a0 += f * W_fc[k];          // uniform -> scalar loads
                a1 += f * W_fc[256 + k];
                a2 += f * W_fc[512 + k];
            }
        }
        int batch = g * NBATCH + b16;
        float* o = out + ((size_t)batch * T_LEN + t) * 3;
        o[0] = a0; o[1] = a1; o[2] = a2;
    }
}

extern "C" void kernel_launch(void* const* d_in, const int* in_sizes, int n_in,
                              void* d_out, int out_size, void* d_ws, size_t ws_size,
                              hipStream_t stream)
{
    const float* X_p      = (const float*)d_in[0];
    const float* X_f      = (const float*)d_in[1];
    const float* noise    = (const float*)d_in[2];
    const float* W_ih_enc = (const float*)d_in[3];
    const float* W_hh_enc = (const float*)d_in[4];
    const float* b_ih_enc = (const float*)d_in[5];
    const float* b_hh_enc = (const float*)d_in[6];
    const float* W_ih_dec = (const float*)d_in[7];
    const float* W_hh_dec = (const float*)d_in[8];
    const float* b_ih_dec = (const float*)d_in[9];
    const float* b_hh_dec = (const float*)d_in[10];
    const float* W_fc     = (const float*)d_in[11];
    const float* b_fc     = (const float*)d_in[12];

    // allow >64 KiB dynamic LDS (idempotent; host-side, graph-capture safe)
    (void)hipFuncSetAttribute((const void*)&gru_fused,
                              hipFuncAttributeMaxDynamicSharedMemorySize, SMEM_BYTES);

    // ws: [0,64K) Wr_enc | [64K,128K) Wr_dec | [128K, +67.1MB) dec Y bf16
    unsigned short* wr_enc = (unsigned short*)d_ws;
    unsigned short* wr_dec = (unsigned short*)((char*)d_ws + (64u << 10));
    unsigned short* Yws    = (unsigned short*)((char*)d_ws + (128u << 10));

    hipLaunchKernelGGL(prep_wr, dim3(32), dim3(256), 0, stream,
        W_hh_enc, W_hh_dec, wr_enc, wr_dec);

    hipLaunchKernelGGL(gru_fused, dim3(NBLK), dim3(NTHREADS), SMEM_BYTES, stream,
        X_p, X_f, W_hh_enc, W_hh_dec, W_ih_enc, W_ih_dec,
        b_ih_enc, b_ih_dec, b_hh_enc, b_hh_dec,
        wr_enc, wr_dec, noise, Yws, W_fc, b_fc, (float*)d_out);
}